// Round 1
// 234.929 us; speedup vs baseline: 1.0009x; 1.0009x over previous
//
#include <hip/hip_runtime.h>

// x: (8, 64, 256, 256) fp32; alpha: (1,64,1,1) fp32
// out = x + alpha[c] * sum_{3x3 zero-padded} |x - neighbor|   (center tap == 0)
//
// One wave (64 lanes x float4) covers one full 256-wide row.
// Software-pipelined rolling window: each wave produces 16 output rows from
// 18 loaded rows (1.125x read amp vs 1.5x before), with a 6-deep float4
// prefetch ring (issue->consume distance = 4 rows) so ~4 global loads stay
// in flight per wave. Fully unrolled: all ring/window indices compile-time
// constant -> registers, no scratch.
// Block = 4 waves = 64-row slab. Grid = 512 images * 4 slabs = 2048 blocks
// (= 8 blocks/CU, 8 waves/SIMD if VGPR <= 64).

constexpr int H = 256;
constexpr int W = 256;
constexpr int C = 64;
constexpr int ROWS = 16;   // output rows per wave
constexpr int Q    = 6;    // prefetch ring depth (rows in flight)

__global__ __launch_bounds__(256) void adc_kernel(
    const float* __restrict__ x,
    const float* __restrict__ alpha,
    float* __restrict__ out)
{
    const int lane = threadIdx.x & 63;
    const int wave = threadIdx.x >> 6;            // 0..3
    const long blk = (long)blockIdx.x;
    const long img = blk >> 2;                    // 0..511 (b*C + c)
    const int  sb  = (int)(blk & 3);              // 64-row slab within image
    const int  y0  = sb * 64 + wave * ROWS;       // first output row of wave
    const int  c   = (int)(img & (C - 1));

    const float  a    = alpha[c];
    const float* imgp = x   + img * (long)(H * W);
    float*       outp = out + img * (long)(H * W);
    const int    w0   = lane * 4;

    auto LOAD = [&](int yy) -> float4 {
        float4 v = make_float4(0.f, 0.f, 0.f, 0.f);
        if (yy >= 0 && yy < H)                    // wave-uniform branch
            v = *(const float4*)(imgp + (long)yy * W + w0);
        return v;
    };

    float4 q[Q];        // raw prefetch ring: slot k%Q holds row y0-1+k
    float  e[3][6];     // expanded 3-row window (6 wide incl. halo)

    auto EXPAND = [&](float4 f, int s3) {
        e[s3][1] = f.x; e[s3][2] = f.y; e[s3][3] = f.z; e[s3][4] = f.w;
        const float left  = __shfl_up(f.w, 1);
        const float right = __shfl_down(f.x, 1);
        e[s3][0] = (lane == 0)  ? 0.f : left;     // w0==0 edge -> zero pad
        e[s3][5] = (lane == 63) ? 0.f : right;    // w0+4==W edge -> zero pad
    };

    // Prologue: fill the ring with rows y0-1 .. y0+4 (k = 0..5).
#pragma unroll
    for (int k = 0; k < Q; ++k)
        q[k] = LOAD(y0 - 1 + k);

    EXPAND(q[0], 0);    // row y0-1
    EXPAND(q[1], 1);    // row y0

    // Main loop, fully unrolled: iteration o emits output row y0+o.
#pragma unroll
    for (int o = 0; o < ROWS; ++o) {
        // Expand the bottom row of this iteration's window (row y0+o+1, k=o+2).
        EXPAND(q[(o + 2) % Q], (o + 2) % 3);

        // Refill the slot freed two iterations ago with row k=o+Q
        // (row y0+o+Q-1); consumed 4 iterations from now.
        if (o <= ROWS + 1 - Q)
            q[o % Q] = LOAD(y0 + o + Q - 1);

        const int ti = o % 3;          // row y0+o-1
        const int mi = (o + 1) % 3;    // row y0+o
        const int bi = (o + 2) % 3;    // row y0+o+1

        float4 res;
        float* rp = &res.x;
#pragma unroll
        for (int j = 0; j < 4; ++j) {
            const float xc = e[mi][j + 1];
            float s = 0.f;
#pragma unroll
            for (int d = 0; d < 3; ++d) {
                s += fabsf(xc - e[ti][j + d]);   // top row, 3 taps
                s += fabsf(xc - e[bi][j + d]);   // bottom row, 3 taps
            }
            s += fabsf(xc - e[mi][j]);           // left
            s += fabsf(xc - e[mi][j + 2]);       // right (center tap is 0)
            rp[j] = fmaf(a, s, xc);
        }
        *(float4*)(outp + (long)(y0 + o) * W + w0) = res;
    }
}

extern "C" void kernel_launch(void* const* d_in, const int* in_sizes, int n_in,
                              void* d_out, int out_size, void* d_ws, size_t ws_size,
                              hipStream_t stream)
{
    const float* x     = (const float*)d_in[0];
    const float* alpha = (const float*)d_in[1];
    float*       out   = (float*)d_out;

    const int grid = 8 * C * (H / 64);   // 512 images * 4 slabs = 2048
    adc_kernel<<<grid, 256, 0, stream>>>(x, alpha, out);
}

// Round 2
// 225.545 us; speedup vs baseline: 1.0426x; 1.0416x over previous
//
#include <hip/hip_runtime.h>

// x: (8, 64, 256, 256) fp32; alpha: (1,64,1,1) fp32
// out = x + alpha[c] * sum_{3x3 zero-padded} |x - neighbor|  (center tap = 0)
//
// One wave (64 lanes x float4) = one full 256-wide row.
// Each wave computes 4 output rows from 6 loaded rows (register halo reuse).
// KEY FIX vs previous rounds: the 6 row-loads are issued as a dedicated
// phase into named float4 registers, pinned above the consume phase with
// sched_barrier(0), and __launch_bounds__(256, 4) relaxes the register
// target so the allocator cannot re-serialize the loads to save VGPRs.
// (At VGPR=32 the old kernel provably could not keep 6 rows live -> each
// wave was a serial chain of ~6 memory latencies -> 82us with both pipes
// <35% busy.)
// Block = 4 waves = 16-row slab. Grid = 512 images * 16 slabs = 8192 blocks
// (4x residency oversubscription for TLP + load balance).

constexpr int H = 256;
constexpr int W = 256;
constexpr int C = 64;

__global__ __launch_bounds__(256, 4) void adc_kernel(
    const float* __restrict__ x,
    const float* __restrict__ alpha,
    float* __restrict__ out)
{
    const int lane = threadIdx.x & 63;
    const int wave = threadIdx.x >> 6;            // 0..3
    const int slab = blockIdx.x;                  // img*16 + s16
    const int img  = slab >> 4;                   // 0..511 (b*C + c)
    const int s16  = slab & 15;
    const int y0   = s16 * 16 + wave * 4;         // first output row of wave
    const int c    = img & (C - 1);

    const float  a    = alpha[c];
    const float* imgp = x   + (long)img * (H * W);
    float*       outp = out + (long)img * (H * W);
    const int    w0   = lane * 4;
    const float* base = imgp + (long)y0 * W + w0;

    // ---- Phase 1: issue all 6 row loads (rows y0-1 .. y0+4) ----
    const float4 z4 = make_float4(0.f, 0.f, 0.f, 0.f);
    float4 c0 = (y0 > 0)     ? *(const float4*)(base - W)     : z4;
    float4 c1 =                *(const float4*)(base);
    float4 c2 =                *(const float4*)(base + W);
    float4 c3 =                *(const float4*)(base + 2 * W);
    float4 c4 =                *(const float4*)(base + 3 * W);
    float4 c5 = (y0 + 4 < H) ? *(const float4*)(base + 4 * W) : z4;

    // Keep the loads above everything that consumes them: all 6 stay in
    // flight together instead of load->wait->use chains.
    __builtin_amdgcn_sched_barrier(0);

    // ---- Phase 2: expand to 6x6 window (halo via shuffles) ----
    float e[6][6];
#define EXPAND_ROW(k, f)                                            \
    {                                                               \
        e[k][1] = (f).x; e[k][2] = (f).y;                           \
        e[k][3] = (f).z; e[k][4] = (f).w;                           \
        const float lft = __shfl_up((f).w, 1);                      \
        const float rgt = __shfl_down((f).x, 1);                    \
        e[k][0] = (lane == 0)  ? 0.f : lft;  /* w0==0   -> pad */   \
        e[k][5] = (lane == 63) ? 0.f : rgt;  /* w0+4==W -> pad */   \
    }
    EXPAND_ROW(0, c0)
    EXPAND_ROW(1, c1)
    EXPAND_ROW(2, c2)
    EXPAND_ROW(3, c3)
    EXPAND_ROW(4, c4)
    EXPAND_ROW(5, c5)
#undef EXPAND_ROW

    // ---- Phase 3: 4 output rows x 4 cols ----
#pragma unroll
    for (int o = 0; o < 4; ++o) {
        float4 res;
        float* rp = &res.x;
#pragma unroll
        for (int j = 0; j < 4; ++j) {
            const float xc = e[o + 1][j + 1];
            float s = 0.f;
#pragma unroll
            for (int r = 0; r < 3; ++r)
#pragma unroll
                for (int d = 0; d < 3; ++d)
                    s += fabsf(xc - e[o + r][j + d]);   // center tap adds 0
            rp[j] = fmaf(a, s, xc);
        }
        *(float4*)(outp + (long)(y0 + o) * W + w0) = res;
    }
}

extern "C" void kernel_launch(void* const* d_in, const int* in_sizes, int n_in,
                              void* d_out, int out_size, void* d_ws, size_t ws_size,
                              hipStream_t stream)
{
    const float* x     = (const float*)d_in[0];
    const float* alpha = (const float*)d_in[1];
    float*       out   = (float*)d_out;

    const int grid = 8 * C * (H / 16);   // 512 images * 16 slabs = 8192
    adc_kernel<<<grid, 256, 0, stream>>>(x, alpha, out);
}